// Round 2
// baseline (549.741 us; speedup 1.0000x reference)
//
#include <hip/hip_runtime.h>
#include <hip/hip_fp16.h>
#include <hip/hip_bf16.h>
#include <math.h>

#define L 8192
#define LOG2L 13
#define B 16
#define CIN 64
#define COUT 64
#define KK 64

#define PI_F 3.14159265358979323846f

// ---------------- kernel 1: partial per-batch min/max of |x| ----------------
__global__ __launch_bounds__(256) void k_reduce1(const float* __restrict__ xr,
                                                 const float* __restrict__ xi,
                                                 float* __restrict__ pmin,
                                                 float* __restrict__ pmax) {
    int bid = blockIdx.x;            // 1024 = 16 batches * 64 slices
    int batch = bid >> 6, slice = bid & 63;
    size_t base = (size_t)batch * CIN * L + (size_t)slice * L;
    int tid = threadIdx.x;
    float mn = 3.4e38f, mx = 0.0f;
    for (int r = 0; r < 32; ++r) {
        int idx = r * 256 + tid;
        float a = xr[base + idx], b = xi[base + idx];
        float m = sqrtf(a * a + b * b);
        mn = fminf(mn, m);
        mx = fmaxf(mx, m);
    }
    __shared__ float smn[4], smx[4];
    for (int off = 32; off >= 1; off >>= 1) {
        mn = fminf(mn, __shfl_down(mn, off));
        mx = fmaxf(mx, __shfl_down(mx, off));
    }
    int wave = tid >> 6;
    if ((tid & 63) == 0) { smn[wave] = mn; smx[wave] = mx; }
    __syncthreads();
    if (tid == 0) {
        for (int w = 1; w < 4; ++w) { mn = fminf(mn, smn[w]); mx = fmaxf(mx, smx[w]); }
        pmin[bid] = mn;
        pmax[bid] = mx;
    }
}

// ---------------- kernel 2: final min/max ----------------
__global__ __launch_bounds__(64) void k_reduce2(const float* __restrict__ pmin,
                                                const float* __restrict__ pmax,
                                                float* __restrict__ mmin,
                                                float* __restrict__ mmax) {
    int b = blockIdx.x, t = threadIdx.x;
    float mn = pmin[b * 64 + t], mx = pmax[b * 64 + t];
    for (int off = 32; off >= 1; off >>= 1) {
        mn = fminf(mn, __shfl_down(mn, off));
        mx = fmaxf(mx, __shfl_down(mx, off));
    }
    if (t == 0) { mmin[b] = mn; mmax[b] = mx; }
}

// ---------------- kernel 3: kernel FFT stats (64-pt DFT, mag+phase) ----------------
__global__ __launch_bounds__(64) void k_kstats(const float* __restrict__ kr,
                                               const float* __restrict__ ki,
                                               float* __restrict__ kmag,
                                               float* __restrict__ kph) {
    int row = blockIdx.x;   // o*64 + j  (4096 rows)
    int k = threadIdx.x;    // output frequency 0..63
    __shared__ float sr[64], si[64];
    sr[k] = kr[row * 64 + k];
    si[k] = ki[row * 64 + k];
    __syncthreads();
    float ar = 0.f, ai = 0.f;
    for (int n = 0; n < 64; ++n) {
        int m = (n * k) & 63;                       // exact mod-64 reduction
        float ang = -2.0f * PI_F * (float)m * (1.0f / 64.0f);
        float s, c;
        __sincosf(ang, &s, &c);
        ar += sr[n] * c - si[n] * s;
        ai += sr[n] * s + si[n] * c;
    }
    kmag[row * 64 + k] = sqrtf(ar * ar + ai * ai);
    kph[row * 64 + k] = atan2f(ai, ar);
}

// ---------------- kernel 4: coupling + forward DIF FFT (per row) ----------------
// output stored in DIF order: storage index p holds frequency bitrev13(p)
// x_fft stored as half2 (re,im) in d_out (exactly out_size*4 bytes)
__global__ __launch_bounds__(512) void k_fwd(const float* __restrict__ xr,
                                             const float* __restrict__ xi,
                                             const float* __restrict__ mmin_,
                                             const float* __restrict__ mmax_,
                                             __half2* __restrict__ xfft) {
    __shared__ float sRe[L];
    __shared__ float sIm[L];
    int row = blockIdx.x;          // b*64 + j
    int b = row >> 6;
    int tid = threadIdx.x;
    float mmin = mmin_[b], mmax = mmax_[b];
    float span = mmax - mmin;
    float invden = 1.0f / (span + 1e-10f);
    size_t base = (size_t)row * L;

    for (int rpt = 0; rpt < L / 512; ++rpt) {
        int idx = rpt * 512 + tid;
        float a = xr[base + idx], c = xi[base + idx];
        float m = sqrtf(a * a + c * c);
        float xn = (m - mmin) * invden;
#pragma unroll
        for (int it = 0; it < 5; ++it) xn = 3.8f * xn * (1.0f - xn);
        float mc = xn * span + mmin;
        float scale = (m > 0.0f) ? (mc / m) : 0.0f;
        sRe[idx] = a * scale;
        sIm[idx] = c * scale;
    }

    // radix-2 DIF, natural in -> bit-reversed out
    for (int s = 0; s < LOG2L; ++s) {
        int lg = LOG2L - 1 - s;
        int len = 1 << lg;
        float fstep = -PI_F / (float)len;
        __syncthreads();
        for (int rpt = 0; rpt < (L / 2) / 512; ++rpt) {
            int t = rpt * 512 + tid;
            int j = t & (len - 1);
            int idx = ((t >> lg) << (lg + 1)) | j;
            float ar = sRe[idx], ai = sIm[idx];
            float br = sRe[idx + len], bi = sIm[idx + len];
            sRe[idx] = ar + br;
            sIm[idx] = ai + bi;
            float dr = ar - br, di = ai - bi;
            float ang = fstep * (float)j;
            float sn, cs;
            __sincosf(ang, &sn, &cs);
            sRe[idx + len] = dr * cs - di * sn;
            sIm[idx + len] = dr * sn + di * cs;
        }
    }
    __syncthreads();

    for (int rpt = 0; rpt < L / 512; ++rpt) {
        int idx = rpt * 512 + tid;
        xfft[base + idx] = __floats2half2_rn(sRe[idx], sIm[idx]);
    }
}

// ---------------- kernel 5: per-frequency complex GEMM ----------------
// out_fft[b,i,p] = sum_j x_fft[b,j,p] * kint[i,j, l=bitrev(p)]   (all in DIF order)
#define PB 32
#define IB 16
#define JC 8
__global__ __launch_bounds__(256) void k_gemm(const __half2* __restrict__ xfft,
                                              const float* __restrict__ kmag,
                                              const float* __restrict__ kph,
                                              __hip_bfloat162* __restrict__ outfft) {
    __shared__ float2 tile[JC][B][PB];   // 32 KB

    int bid = blockIdx.x;          // 256 p-blocks * 4 i-blocks, i-blocks adjacent
    int ib = bid & 3;
    int pb = bid >> 2;
    int p0 = pb * PB;
    int i0 = ib * IB;
    int tid = threadIdx.x;
    int pl = tid & 31;             // p lane
    int g = tid >> 5;              // group 0..7, 2 i's each
    int p = p0 + pl;
    int l = (int)(__brev((unsigned)p) >> 19);   // actual frequency

    // interpolation parameters for this frequency
    float pos = ((float)l + 0.5f) * ((float)KK / (float)L) - 0.5f;
    pos = fminf(fmaxf(pos, 0.0f), (float)(KK - 1));
    int i0k = (int)floorf(pos);
    int i1k = min(i0k + 1, KK - 1);
    float w = pos - (float)i0k;

    float accR[B][2], accI[B][2];
#pragma unroll
    for (int bb = 0; bb < B; ++bb) {
        accR[bb][0] = 0.f; accR[bb][1] = 0.f;
        accI[bb][0] = 0.f; accI[bb][1] = 0.f;
    }

    for (int jc = 0; jc < CIN; jc += JC) {
        __syncthreads();
        // stage x_fft[b, jc..jc+7, p-block] into LDS (f16 -> f32)
        for (int rpt = 0; rpt < (JC * B * PB) / 256; ++rpt) {
            int lin = rpt * 256 + tid;
            int pp = lin & (PB - 1);
            int bj = lin >> 5;         // 0..127
            int jj = bj >> 4;          // 0..7
            int bb = bj & 15;
            __half2 v = xfft[((size_t)(bb * CIN + jc + jj)) * L + p0 + pp];
            tile[jj][bb][pp] = make_float2(__low2float(v), __high2float(v));
        }
        __syncthreads();

        for (int jj = 0; jj < JC; ++jj) {
            int j = jc + jj;
            float krr[2], kii[2];
#pragma unroll
            for (int q = 0; q < 2; ++q) {
                int i = i0 + g * 2 + q;
                int kb = (i * CIN + j) * KK;
                float m0 = kmag[kb + i0k], m1 = kmag[kb + i1k];
                float p0v = kph[kb + i0k], p1v = kph[kb + i1k];
                float mm = m0 * (1.0f - w) + m1 * w;
                float ph = p0v * (1.0f - w) + p1v * w;
                float sn, cs;
                __sincosf(ph, &sn, &cs);
                krr[q] = mm * cs;
                kii[q] = mm * sn;
            }
#pragma unroll
            for (int bb = 0; bb < B; ++bb) {
                float2 x = tile[jj][bb][pl];
                accR[bb][0] += x.x * krr[0] - x.y * kii[0];
                accI[bb][0] += x.x * kii[0] + x.y * krr[0];
                accR[bb][1] += x.x * krr[1] - x.y * kii[1];
                accI[bb][1] += x.x * kii[1] + x.y * krr[1];
            }
        }
    }

#pragma unroll
    for (int q = 0; q < 2; ++q) {
        int i = i0 + g * 2 + q;
#pragma unroll
        for (int bb = 0; bb < B; ++bb) {
            __hip_bfloat162 o;
            o.x = __float2bfloat16(accR[bb][q]);
            o.y = __float2bfloat16(accI[bb][q]);
            outfft[((size_t)(bb * COUT + i)) * L + p] = o;
        }
    }
}

// ---------------- kernel 6: inverse DIT FFT + activation (real part only) ----------------
__global__ __launch_bounds__(512) void k_ifft(const __hip_bfloat162* __restrict__ outfft,
                                              const float* __restrict__ alpha_,
                                              float* __restrict__ out) {
    __shared__ float sRe[L];
    __shared__ float sIm[L];
    int row = blockIdx.x;          // b*64 + i
    int tid = threadIdx.x;
    float alpha = alpha_[0];
    size_t base = (size_t)row * L;

    for (int rpt = 0; rpt < L / 512; ++rpt) {
        int idx = rpt * 512 + tid;
        __hip_bfloat162 v = outfft[base + idx];
        sRe[idx] = __bfloat162float(v.x);
        sIm[idx] = __bfloat162float(v.y);
    }

    // radix-2 DIT inverse, bit-reversed in -> natural out, +i twiddles
    for (int s = 0; s < LOG2L; ++s) {
        int len = 1 << s;
        float fstep = PI_F / (float)len;
        __syncthreads();
        for (int rpt = 0; rpt < (L / 2) / 512; ++rpt) {
            int t = rpt * 512 + tid;
            int j = t & (len - 1);
            int idx = ((t >> s) << (s + 1)) | j;
            float ang = fstep * (float)j;
            float sn, cs;
            __sincosf(ang, &sn, &cs);
            float br = sRe[idx + len], bi = sIm[idx + len];
            float tr = br * cs - bi * sn;
            float ti = br * sn + bi * cs;
            float ar = sRe[idx], ai = sIm[idx];
            sRe[idx] = ar + tr;
            sIm[idx] = ai + ti;
            sRe[idx + len] = ar - tr;
            sIm[idx + len] = ai - ti;
        }
    }
    __syncthreads();

    const float invN = 1.0f / (float)L;
    for (int rpt = 0; rpt < L / 512; ++rpt) {
        int idx = rpt * 512 + tid;
        float act = sinf(alpha * (float)idx);
        out[base + idx] = sRe[idx] * act * invN;   // real part only
    }
}

// ---------------- launch ----------------
extern "C" void kernel_launch(void* const* d_in, const int* in_sizes, int n_in,
                              void* d_out, int out_size, void* d_ws, size_t ws_size,
                              hipStream_t stream) {
    const float* xr = (const float*)d_in[0];
    const float* xi = (const float*)d_in[1];
    const float* kr = (const float*)d_in[2];
    const float* ki = (const float*)d_in[3];
    const float* alpha = (const float*)d_in[4];
    float* out = (float*)d_out;

    // ws layout (total ~35.7 MB):
    //   [0, 33.5MB)   out_fft as bf16x2 (B*COUT*L complex)
    //   [+0MB, +1MB)  kmag   (COUT*CIN*KK f32)
    //   [+1MB, +2MB)  kph
    //   small: pmin/pmax/mmin/mmax
    char* ws = (char*)d_ws;
    size_t OFFT_BYTES = (size_t)B * COUT * L * 4;          // 33,554,432
    __hip_bfloat162* outfft = (__hip_bfloat162*)ws;
    float* kmag = (float*)(ws + OFFT_BYTES);
    float* kph  = (float*)(ws + OFFT_BYTES + (size_t)COUT * CIN * KK * 4);
    float* pmin = (float*)(ws + OFFT_BYTES + (size_t)2 * COUT * CIN * KK * 4);
    float* pmax = pmin + 1024;
    float* mmin = pmax + 1024;
    float* mmax = mmin + 16;

    __half2* xfft = (__half2*)d_out;   // exactly out_size*4 bytes; overwritten by k_ifft

    hipLaunchKernelGGL(k_reduce1, dim3(1024), dim3(256), 0, stream, xr, xi, pmin, pmax);
    hipLaunchKernelGGL(k_reduce2, dim3(16), dim3(64), 0, stream, pmin, pmax, mmin, mmax);
    hipLaunchKernelGGL(k_kstats, dim3(4096), dim3(64), 0, stream, kr, ki, kmag, kph);
    hipLaunchKernelGGL(k_fwd, dim3(1024), dim3(512), 0, stream, xr, xi, mmin, mmax, xfft);
    hipLaunchKernelGGL(k_gemm, dim3(1024), dim3(256), 0, stream, xfft, kmag, kph, outfft);
    hipLaunchKernelGGL(k_ifft, dim3(1024), dim3(512), 0, stream, outfft, alpha, out);
}